// Round 5
// baseline (185.870 us; speedup 1.0000x reference)
//
#include <hip/hip_runtime.h>

// PyFlowODE: Heun integration of dx/dt = (x - q(x,t))/t with Nadaraya-Watson
// Gaussian RBF retrieval. N=2048 queries (d=8), B=4096 bank, T=16 steps.
//
// Round-2 structure (resubmitted; repeated infra failures, never benched):
//  - 256 blocks x 512 threads (8 waves). LDS: x0 staged once (128 KB split
//    lo/hi float4 arrays, conflict-free ds_read_b128) + 768 B merge buffer.
//  - Each wave processes TWO queries over HALF the bank (32 entries/lane):
//    every 32 B LDS entry read feeds two dot/accumulate pipelines (2x LDS
//    amortization vs round 1). Wave pairs (w, w^1) merge partials via LDS.
//  - Softmax tracked as running MIN of ||z||^2 (zz-domain): weight
//    w = exp2(fma(c0, zz, t0)) -- one fma+exp2 per entry, no per-entry sub.
//    Deferred rescale (threshold 40 log2-units) keeps it exact-robust.
//  - t=1 eval: alpha=0 -> all logits equal -> q = mean(x0) exactly.
//    mean computed once at staging; first eval deleted.

#define NQ     2048
#define NB     4096
#define TSTEPS 16
#define BLOCK  512

#if defined(__has_builtin)
#if __has_builtin(__builtin_amdgcn_exp2f)
#define EXP2(x) __builtin_amdgcn_exp2f(x)
#endif
#endif
#ifndef EXP2
#define EXP2(x) exp2f(x)
#endif

// Evaluate G(x, t) for this wave's TWO queries (xq wave-uniform per query).
// Each wave covers bank half h; partials merged with partner wave via mrg.
__device__ __forceinline__ void eval_pair(
        const float4* __restrict__ lds_lo,
        const float4* __restrict__ lds_hi,
        float (*mrg)[2][12],
        const float (&xq)[2][8], float t, int lane, int h, int w,
        float (&Gout)[2][8])
{
    const float c0      = -0.72134752044448170f / (t * t);   // -0.5*log2(e)/t^2
    const float alpha   = 1.0f - t;
    const float thr_off = 40.0f / c0;                        // negative
    float mz[2] = {3.0e38f, 3.0e38f};   // running min of zz (per lane)
    float th[2] = {3.0e38f, 3.0e38f};   // rescale trigger: zz < th
    float t0[2] = {0.0f, 0.0f};         // -c0*mz  (valid after first rescale)
    float s[2]  = {0.0f, 0.0f};
    float q[2][8];
#pragma unroll
    for (int qq = 0; qq < 2; ++qq)
#pragma unroll
        for (int j = 0; j < 8; ++j) q[qq][j] = 0.0f;

    const int b0 = lane + h * 2048;

#pragma unroll 2
    for (int g = 0; g < 8; ++g) {
        float4 lo[4], hi[4];
        float  zz[2][4];
#pragma unroll
        for (int e = 0; e < 4; ++e) {
            const int b = b0 + g * 256 + e * 64;   // lanes contiguous: conflict-free
            lo[e] = lds_lo[b];
            hi[e] = lds_hi[b];
#pragma unroll
            for (int qq = 0; qq < 2; ++qq) {
                float z, acc;
                z = fmaf(-alpha, lo[e].x, xq[qq][0]); acc = z * z;
                z = fmaf(-alpha, lo[e].y, xq[qq][1]); acc = fmaf(z, z, acc);
                z = fmaf(-alpha, lo[e].z, xq[qq][2]); acc = fmaf(z, z, acc);
                z = fmaf(-alpha, lo[e].w, xq[qq][3]); acc = fmaf(z, z, acc);
                z = fmaf(-alpha, hi[e].x, xq[qq][4]); acc = fmaf(z, z, acc);
                z = fmaf(-alpha, hi[e].y, xq[qq][5]); acc = fmaf(z, z, acc);
                z = fmaf(-alpha, hi[e].z, xq[qq][6]); acc = fmaf(z, z, acc);
                z = fmaf(-alpha, hi[e].w, xq[qq][7]); acc = fmaf(z, z, acc);
                zz[qq][e] = acc;
            }
        }
#pragma unroll
        for (int qq = 0; qq < 2; ++qq) {
            const float bz = fminf(fminf(zz[qq][0], zz[qq][1]),
                                   fminf(zz[qq][2], zz[qq][3]));
            if (__any(bz < th[qq])) {      // wave-uniform; always taken at g=0
                const float mzn = fminf(mz[qq], bz);
                const float c = EXP2(c0 * (mz[qq] - mzn));  // first time: exp2(-inf)=0
                s[qq] *= c;
#pragma unroll
                for (int j = 0; j < 8; ++j) q[qq][j] *= c;
                mz[qq] = mzn;
                th[qq] = mzn + thr_off;
                t0[qq] = -c0 * mzn;
            }
#pragma unroll
            for (int e = 0; e < 4; ++e) {
                const float wgt = EXP2(fmaf(c0, zz[qq][e], t0[qq]));  // underflow->0 ok
                s[qq] += wgt;
                q[qq][0] = fmaf(wgt, lo[e].x, q[qq][0]);
                q[qq][1] = fmaf(wgt, lo[e].y, q[qq][1]);
                q[qq][2] = fmaf(wgt, lo[e].z, q[qq][2]);
                q[qq][3] = fmaf(wgt, lo[e].w, q[qq][3]);
                q[qq][4] = fmaf(wgt, hi[e].x, q[qq][4]);
                q[qq][5] = fmaf(wgt, hi[e].y, q[qq][5]);
                q[qq][6] = fmaf(wgt, hi[e].z, q[qq][6]);
                q[qq][7] = fmaf(wgt, hi[e].w, q[qq][7]);
            }
        }
    }

    // ---- per-wave cross-lane reduce (butterfly; all lanes get wave totals) ----
#pragma unroll
    for (int qq = 0; qq < 2; ++qq) {
        float mw = mz[qq];
#pragma unroll
        for (int off = 32; off >= 1; off >>= 1)
            mw = fminf(mw, __shfl_xor(mw, off));
        const float c = EXP2(c0 * (mz[qq] - mw));   // mz>=mw -> c<=1
        s[qq] *= c;
#pragma unroll
        for (int j = 0; j < 8; ++j) q[qq][j] *= c;
        mz[qq] = mw;
#pragma unroll
        for (int off = 32; off >= 1; off >>= 1) {
            s[qq] += __shfl_xor(s[qq], off);
#pragma unroll
            for (int j = 0; j < 8; ++j) q[qq][j] += __shfl_xor(q[qq][j], off);
        }
    }

    // ---- cross-wave (pair) merge via LDS ----
    if (lane == 0) {
#pragma unroll
        for (int qq = 0; qq < 2; ++qq) {
            float* p = mrg[w][qq];
            p[0] = mz[qq];
            p[1] = s[qq];
#pragma unroll
            for (int j = 0; j < 8; ++j) p[2 + j] = q[qq][j];
        }
    }
    __syncthreads();
    const int pw = w ^ 1;
    const float invT = 1.0f / t;
#pragma unroll
    for (int qq = 0; qq < 2; ++qq) {
        const float* p = mrg[pw][qq];
        const float mzb = p[0], sb = p[1];
        const float M  = fminf(mz[qq], mzb);
        const float ca = EXP2(c0 * (mz[qq] - M));
        const float cb = EXP2(c0 * (mzb  - M));
        const float S  = ca * s[qq] + cb * sb;   // commutative: both waves identical
        const float invS = 1.0f / S;
#pragma unroll
        for (int j = 0; j < 8; ++j) {
            const float Q = ca * q[qq][j] + cb * p[2 + j];
            Gout[qq][j] = fmaf(-Q, invS, xq[qq][j]) * invT;
        }
    }
    __syncthreads();   // protect mrg before next eval's write
}

__global__ __launch_bounds__(BLOCK, 2) void flow_ode_kernel(
        const float* __restrict__ x1,
        const float* __restrict__ x0,
        float* __restrict__ out)
{
    __shared__ float4 lds_lo[NB];       // x0[b][0:4]
    __shared__ float4 lds_hi[NB];       // x0[b][4:8]
    __shared__ float  mrg[8][2][12];    // per-wave partials / staging wavesums

    const int tid  = threadIdx.x;
    const int w    = tid >> 6;
    const int lane = tid & 63;

    // ---- stage x0 (128 KB) + per-thread partial column sums for mean ----
    float sm[8];
#pragma unroll
    for (int j = 0; j < 8; ++j) sm[j] = 0.0f;
#pragma unroll
    for (int i = 0; i < NB / BLOCK; ++i) {
        const int b = tid + i * BLOCK;
        const float4* p = reinterpret_cast<const float4*>(x0) + 2 * b;
        const float4 lo = p[0], hi = p[1];
        lds_lo[b] = lo;
        lds_hi[b] = hi;
        sm[0] += lo.x; sm[1] += lo.y; sm[2] += lo.z; sm[3] += lo.w;
        sm[4] += hi.x; sm[5] += hi.y; sm[6] += hi.z; sm[7] += hi.w;
    }
#pragma unroll
    for (int off = 32; off >= 1; off >>= 1)
#pragma unroll
        for (int j = 0; j < 8; ++j) sm[j] += __shfl_xor(sm[j], off);
    if (lane == 0) {
#pragma unroll
        for (int j = 0; j < 8; ++j) mrg[w][0][j] = sm[j];
    }
    __syncthreads();
    float mean[8];
#pragma unroll
    for (int j = 0; j < 8; ++j) {
        float acc = 0.0f;
#pragma unroll
        for (int wv = 0; wv < 8; ++wv) acc += mrg[wv][0][j];
        mean[j] = acc * (1.0f / (float)NB);
    }
    __syncthreads();

    // ---- per-wave query assignment: 2 queries, bank half h ----
    const int h     = w & 1;
    const int pair  = w >> 1;
    const int qbase = blockIdx.x * 8 + pair * 2;

    float xt[2][8], G1[2][8];
#pragma unroll
    for (int qq = 0; qq < 2; ++qq) {
        const float4* p = reinterpret_cast<const float4*>(x1) + 2 * (qbase + qq);
        const float4 a = p[0], b4 = p[1];
        xt[qq][0] = a.x;  xt[qq][1] = a.y;  xt[qq][2] = a.z;  xt[qq][3] = a.w;
        xt[qq][4] = b4.x; xt[qq][5] = b4.y; xt[qq][6] = b4.z; xt[qq][7] = b4.w;
    }
    // G1 at t=1: alpha=0 -> uniform weights -> q = mean(x0) exactly
#pragma unroll
    for (int qq = 0; qq < 2; ++qq)
#pragma unroll
        for (int j = 0; j < 8; ++j) G1[qq][j] = xt[qq][j] - mean[j];

    const float hstep = 0.0625f;   // 1/16
    for (int i = 1; i < TSTEPS; ++i) {
        const float t = 1.0f - hstep * (float)i;   // exact in f32
        float xe[2][8], G2[2][8];
#pragma unroll
        for (int qq = 0; qq < 2; ++qq)
#pragma unroll
            for (int j = 0; j < 8; ++j)
                xe[qq][j] = fmaf(-hstep, G1[qq][j], xt[qq][j]);   // Euler predictor
        eval_pair(lds_lo, lds_hi, mrg, xe, t, lane, h, w, G2);
#pragma unroll
        for (int qq = 0; qq < 2; ++qq)
#pragma unroll
            for (int j = 0; j < 8; ++j) {
                xt[qq][j] = fmaf(-0.03125f, G1[qq][j] + G2[qq][j], xt[qq][j]);
                G1[qq][j] = G2[qq][j];
            }
    }

    if (h == 0 && lane == 0) {
#pragma unroll
        for (int qq = 0; qq < 2; ++qq) {
            float4 a, b4;
            a.x  = xt[qq][0]; a.y  = xt[qq][1]; a.z  = xt[qq][2]; a.w  = xt[qq][3];
            b4.x = xt[qq][4]; b4.y = xt[qq][5]; b4.z = xt[qq][6]; b4.w = xt[qq][7];
            float4* o = reinterpret_cast<float4*>(out + (qbase + qq) * 8);
            o[0] = a;
            o[1] = b4;
        }
    }
}

extern "C" void kernel_launch(void* const* d_in, const int* in_sizes, int n_in,
                              void* d_out, int out_size, void* d_ws, size_t ws_size,
                              hipStream_t stream) {
    const float* x1 = (const float*)d_in[0];   // (2048, 8)
    const float* x0 = (const float*)d_in[1];   // (4096, 8)
    float* out = (float*)d_out;                // (2048, 8)

    flow_ode_kernel<<<NQ / 8, BLOCK, 0, stream>>>(x1, x0, out);
}